// Round 7
// baseline (368.948 us; speedup 1.0000x reference)
//
#include <hip/hip_runtime.h>

// Fused 2-layer LSTM (H=64) + Dense(64,sigmoid) + Dense(1,sigmoid), MFMA bf16.
// Transposed-z + UNIFIED waves: each of 16 waves computes one L1 tile (step k)
// and one L2 tile (step k-1) per barrier window -> balanced waves, 2 independent
// chains/wave, shared h1[k-1] fragments. One barrier per window.
// B=4096, T=256, F=32. WG = 1024 threads = 16 waves, BB=16 batch rows, grid 256.
// Tile T=w covers gate-unit rows {unit=4T+(m>>2), gate=m&3}; lane (n,q) owns
// cell (batch n, unit 4T+q), gates r=0..3 in its 4 accumulators.
// Activation scales folded into weights (i,f,o: -log2e; g: +2*log2e); cell
// state kept pre-scaled by 2*log2e. Bias enters as the MFMA C operand.
// ALL bf16 packs are RNE — round-half-up in the recurrence cost 5x accuracy
// (round-6 post-mortem: biased rounding integrates over 256 steps).
// MFMA 16x16x32 layouts (learn_hip-verified):
//   A[m=lane&15][k=(lane>>4)*8+j], B[k=(lane>>4)*8+j][n=lane&15],
//   C/D: col=lane&15, row=(lane>>4)*4+reg.

typedef __attribute__((ext_vector_type(8))) short short8;
typedef __attribute__((ext_vector_type(4))) float floatx4;
typedef __attribute__((ext_vector_type(2))) float floatx2;

__device__ __forceinline__ float ex2(float x){ return __builtin_amdgcn_exp2f(x); }
__device__ __forceinline__ float rcp_(float x){ return __builtin_amdgcn_rcpf(x); }
__device__ __forceinline__ float sigm(float x){ return rcp_(1.0f + ex2(-1.44269504f*x)); }
__device__ __forceinline__ unsigned bfbits(float f){       // RNE f32->bf16 (raw bits)
    unsigned u = __builtin_bit_cast(unsigned, f);
    u += 0x7FFFu + ((u >> 16) & 1u);
    return u >> 16;
}
__device__ __forceinline__ short f2bf(float f){ return (short)bfbits(f); }
__device__ __forceinline__ unsigned pack_bf2(float a, float b){
    return bfbits(a) | (bfbits(b) << 16);
}

#define MFMA_BF16 __builtin_amdgcn_mfma_f32_16x16x32_bf16

// gate math for one cell: z = (i,f,g,o) pre-scaled; updates c, writes bf16 h (RNE).
#define CELL(zv, cc, wptr) do {                                          \
    float e0 = ex2((zv)[0]), e1 = ex2((zv)[1]);                          \
    float e2 = ex2((zv)[2]), e3 = ex2((zv)[3]);                          \
    float iv = rcp_(1.0f + e0);                                          \
    float fv = rcp_(1.0f + e1);                                          \
    float rg = rcp_(1.0f + e2);                                          \
    float ov = rcp_(1.0f + e3);                                          \
    float gp = fmaf(-5.77078016f, rg, 2.88539008f);   /* 2LG*tanh(zg) */ \
    (cc) = fmaf(fv, (cc), iv * gp);                                      \
    float th = fmaf(-2.0f, rcp_(1.0f + ex2(cc)), 1.0f);                  \
    *(wptr) = f2bf(ov * th);                                             \
} while (0)

__global__ __launch_bounds__(1024, 1)
void lstm2_uni(const float* __restrict__ x,
               const float* __restrict__ W1, const float* __restrict__ U1, const float* __restrict__ b1,
               const float* __restrict__ W2, const float* __restrict__ U2, const float* __restrict__ b2,
               const float* __restrict__ Wd, const float* __restrict__ bd,
               const float* __restrict__ Wo, const float* __restrict__ bo,
               float* __restrict__ out)
{
    __shared__ __align__(16) short h1s[2 * 1152];   // [par][batch*72 + unit]
    __shared__ __align__(16) short h2s[2 * 1152];
    __shared__ __align__(16) short xss[2 * 640];    // [par][batch*40 + feat]
    __shared__ float psum[4][16];

    const int tid  = threadIdx.x;
    const int w    = tid >> 6;            // tile T = w, 0..15
    const int lane = tid & 63;
    const int n    = lane & 15;           // batch row (B-col / C-col)
    const int q    = lane >> 4;           // quad
    const int b0   = blockIdx.x * 16;

    const float LG = 1.44269504f;         // log2(e)

    // A-frag row role: m=n -> (unit_local = n>>2, gate = n&3)
    const int ugl = n >> 2;
    const int gA  = n & 3;
    const float sA = (gA == 2) ? (2.0f * LG) : (-LG);
    const int ncol = gA * 64 + w * 4 + ugl;   // column in the [*,256] weights

    // ---- one-time: weight A-fragments + bias C vectors ----
    short8  Wa1[3], Wa2[4];
    floatx4 bC1, bC2;
#pragma unroll
    for (int j = 0; j < 8; ++j) {
        const int k = q * 8 + j;
        Wa1[0][j] = f2bf(W1[k * 256 + ncol] * sA);          // K: x features
        Wa1[1][j] = f2bf(U1[k * 256 + ncol] * sA);          // K: h1 units 0-31
        Wa1[2][j] = f2bf(U1[(32 + k) * 256 + ncol] * sA);   // K: h1 units 32-63
        Wa2[0][j] = f2bf(W2[k * 256 + ncol] * sA);          // K: h1 units 0-31
        Wa2[1][j] = f2bf(W2[(32 + k) * 256 + ncol] * sA);
        Wa2[2][j] = f2bf(U2[k * 256 + ncol] * sA);          // K: h2 units 0-31
        Wa2[3][j] = f2bf(U2[(32 + k) * 256 + ncol] * sA);
    }
#pragma unroll
    for (int r = 0; r < 4; ++r) {
        const float sr = (r == 2) ? (2.0f * LG) : (-LG);
        bC1[r] = b1[r * 64 + w * 4 + q] * sr;
        bC2[r] = b2[r * 64 + w * 4 + q] * sr;
    }

    // ---- zero parity-1 h buffers (h1[-1], h2[-1]) ----
    if (tid < 576) {
        ((unsigned*)(h1s + 1152))[tid] = 0u;
        ((unsigned*)(h2s + 1152))[tid] = 0u;
    }

    // ---- x staging (tid<256): 2 fp32 of batch row (tid>>4) per step ----
    const int xr = tid >> 4;
    const int xc = (tid & 15) * 2;
    const float* xrow = x + (size_t)(b0 + xr) * 8192 + xc;   // T*F = 8192
    floatx2 xv0;
    if (tid < 256) {
        floatx2 v = *(const floatx2*)xrow;                    // x[0] -> xss[0]
        *(unsigned*)&xss[xr * 40 + xc] = pack_bf2(v.x, v.y);
        xv0 = *(const floatx2*)(xrow + 32);                   // x[1]
    }
    __syncthreads();

    // lane-invariant LDS sub-addresses (loop-hoisted)
    const int rdA = n * 72 + q * 8;        // h frag lo
    const int rdB = rdA + 32;              // h frag hi
    const int rdX = n * 40 + q * 8;        // x frag
    const int wrH = n * 72 + w * 4 + q;    // this lane's h cell slot

    float c1 = 0.0f, c2 = 0.0f;            // cell state, pre-scaled by 2*log2e

    // ================= window 0: L1 step 0 only =================
    {
        short8 bx  = *(const short8*)&xss[rdX];               // par=0
        short8 h1a = *(const short8*)&h1s[1152 + rdA];        // zeros
        short8 h1c = *(const short8*)&h1s[1152 + rdB];
        floatx4 z1 = bC1;
        z1 = MFMA_BF16(Wa1[0], bx,  z1, 0, 0, 0);
        z1 = MFMA_BF16(Wa1[1], h1a, z1, 0, 0, 0);
        z1 = MFMA_BF16(Wa1[2], h1c, z1, 0, 0, 0);
        CELL(z1, c1, &h1s[0 + wrH]);                          // h1[0] -> par 0
        if (tid < 256) {                                      // stage x[1]
            *(unsigned*)&xss[640 + xr * 40 + xc] = pack_bf2(xv0.x, xv0.y);
            xv0 = *(const floatx2*)(xrow + 64);               // x[2]
        }
        __syncthreads();
    }

    // ================= windows 1..255: L1 step k + L2 step k-1 =================
    for (int k = 1; k < 256; ++k) {
        const int par = k & 1, pax = par ^ 1;
        const int oR  = pax * 1152;       // h1[k-1] read base
        const int oW1 = par * 1152;       // h1[k]   write base
        const int oR2 = par * 1152;       // h2[k-2] read base
        const int oW2 = pax * 1152;       // h2[k-1] write base
        const int oX  = par * 640;        // x[k]    read base

        short8 bx  = *(const short8*)&xss[oX + rdX];
        short8 h1a = *(const short8*)&h1s[oR + rdA];          // shared by L1+L2
        short8 h1c = *(const short8*)&h1s[oR + rdB];
        short8 h2a = *(const short8*)&h2s[oR2 + rdA];
        short8 h2c = *(const short8*)&h2s[oR2 + rdB];

        floatx4 z1 = bC1;
        z1 = MFMA_BF16(Wa1[0], bx,  z1, 0, 0, 0);
        z1 = MFMA_BF16(Wa1[1], h1a, z1, 0, 0, 0);
        z1 = MFMA_BF16(Wa1[2], h1c, z1, 0, 0, 0);
        floatx4 z2 = bC2;
        z2 = MFMA_BF16(Wa2[0], h1a, z2, 0, 0, 0);
        z2 = MFMA_BF16(Wa2[1], h1c, z2, 0, 0, 0);
        z2 = MFMA_BF16(Wa2[2], h2a, z2, 0, 0, 0);
        z2 = MFMA_BF16(Wa2[3], h2c, z2, 0, 0, 0);

        CELL(z1, c1, &h1s[oW1 + wrH]);                        // h1[k]
        CELL(z2, c2, &h2s[oW2 + wrH]);                        // h2[k-1]

        if (tid < 256 && k < 255) {                           // stage x[k+1]
            *(unsigned*)&xss[pax * 640 + xr * 40 + xc] = pack_bf2(xv0.x, xv0.y);
            if (k < 254) xv0 = *(const floatx2*)(xrow + (size_t)(k + 2) * 32);
        }
        __syncthreads();
    }

    // ================= window 256: L2 step 255 only =================
    {
        // par=0, pax=1: h1[255] in h1s[1*1152], h2[254] in h2s[0], write h2s[1]
        short8 h1a = *(const short8*)&h1s[1152 + rdA];
        short8 h1c = *(const short8*)&h1s[1152 + rdB];
        short8 h2a = *(const short8*)&h2s[0 + rdA];
        short8 h2c = *(const short8*)&h2s[0 + rdB];
        floatx4 z2 = bC2;
        z2 = MFMA_BF16(Wa2[0], h1a, z2, 0, 0, 0);
        z2 = MFMA_BF16(Wa2[1], h1c, z2, 0, 0, 0);
        z2 = MFMA_BF16(Wa2[2], h2a, z2, 0, 0, 0);
        z2 = MFMA_BF16(Wa2[3], h2c, z2, 0, 0, 0);
        CELL(z2, c2, &h2s[1152 + wrH]);                       // h2[255]
        __syncthreads();
    }

    // ---- epilogue (waves 8-11): Dense(64,sigmoid) + Dense(1,sigmoid) ----
    if (w >= 8 && w < 12) {
        const int wv = w - 8;
        const int colD = wv * 16 + n;
        short8 wd0, wd1;
#pragma unroll
        for (int j = 0; j < 8; ++j) {
            wd0[j] = f2bf(Wd[(q * 8 + j) * 64 + colD] * (-LG));
            wd1[j] = f2bf(Wd[(32 + q * 8 + j) * 64 + colD] * (-LG));
        }
        short8 hA0 = *(const short8*)&h2s[1152 + rdA];
        short8 hA1 = *(const short8*)&h2s[1152 + rdB];
        const float bdv = bd[colD] * (-LG);
        floatx4 dacc = { bdv, bdv, bdv, bdv };
        dacc = MFMA_BF16(hA0, wd0, dacc, 0, 0, 0);
        dacc = MFMA_BF16(hA1, wd1, dacc, 0, 0, 0);
        const float wo = Wo[colD];
#pragma unroll
        for (int r = 0; r < 4; ++r) {
            float p = rcp_(1.0f + ex2(dacc[r])) * wo;   // sigm (scale folded)
            p += __shfl_xor(p, 1, 64);
            p += __shfl_xor(p, 2, 64);
            p += __shfl_xor(p, 4, 64);
            p += __shfl_xor(p, 8, 64);                  // sum over 16 dense units
            if (n == 0) psum[wv][q * 4 + r] = p;
        }
    }
    __syncthreads();
    if (tid < 16) {
        float s = psum[0][tid] + psum[1][tid] + psum[2][tid] + psum[3][tid] + bo[0];
        out[b0 + tid] = sigm(s);
    }
}

extern "C" void kernel_launch(void* const* d_in, const int* in_sizes, int n_in,
                              void* d_out, int out_size, void* d_ws, size_t ws_size,
                              hipStream_t stream) {
    (void)in_sizes; (void)n_in; (void)d_ws; (void)ws_size; (void)out_size;
    const float* x  = (const float*)d_in[0];
    const float* W1 = (const float*)d_in[1];
    const float* U1 = (const float*)d_in[2];
    const float* b1 = (const float*)d_in[3];
    const float* W2 = (const float*)d_in[4];
    const float* U2 = (const float*)d_in[5];
    const float* b2 = (const float*)d_in[6];
    const float* Wd = (const float*)d_in[7];
    const float* bd = (const float*)d_in[8];
    const float* Wo = (const float*)d_in[9];
    const float* bo = (const float*)d_in[10];
    lstm2_uni<<<dim3(256), dim3(1024), 0, stream>>>(
        x, W1, U1, b1, W2, U2, b2, Wd, bd, Wo, bo, (float*)d_out);
}